// Round 2
// baseline (4117.487 us; speedup 1.0000x reference)
//
#include <hip/hip_runtime.h>
#include <cstdint>
#include <cstddef>

typedef unsigned short u16;
typedef __attribute__((ext_vector_type(8))) short short8;
typedef __attribute__((ext_vector_type(16))) float f32x16;

#define XT_HSTRIDE 18432      /* 2*36*256 */
#define XT_BSTRIDE 1308672    /* 71*18432 */
#define K_TOT 20736
#define N_TOT 32768
#define M_TOT 1024

__device__ __forceinline__ u16 f2bf(float f) {
  uint32_t u = __builtin_bit_cast(uint32_t, f);
  u = (u + 0x7fffu + ((u >> 16) & 1u)) >> 16;
  return (u16)u;
}
__device__ __forceinline__ float bf2f(u16 h) {
  uint32_t u = ((uint32_t)h) << 16;
  return __builtin_bit_cast(float, u);
}
__device__ __forceinline__ void glds16(const void* g, void* l) {
  __builtin_amdgcn_global_load_lds((const __attribute__((address_space(1))) void*)g,
                                   (__attribute__((address_space(3))) void*)l, 16, 0, 0);
}

// ---- pack weights: Wb[m][pos*256+c] = bf16(W[m][c][kh][kw]) ----
__global__ __launch_bounds__(256) void pack_w(const float* __restrict__ W,
                                              u16* __restrict__ Wb) {
  __shared__ u16 wl[20736];
  const int m = blockIdx.x;
  const int t = threadIdx.x;
  const size_t base = (size_t)m * K_TOT;
  for (int i = t; i < K_TOT; i += 256) {
    float f = W[base + i];          // input layout per m: (c, pos), i = c*81+pos
    int c = i / 81;
    int pos = i - c * 81;
    wl[pos * 256 + c] = f2bf(f);
  }
  __syncthreads();
  for (int i = t; i < K_TOT; i += 256) Wb[base + i] = wl[i];
}

// ---- pack x: xT[b][h][par][j][c] = bf16(x[b][c][h][2j+par]) ----
__global__ __launch_bounds__(256) void pack_x(const float* __restrict__ X,
                                              u16* __restrict__ xT) {
  __shared__ u16 xl[256 * 73];
  const int h = blockIdx.x;   // 0..70
  const int b = blockIdx.y;   // 0..31
  const int t = threadIdx.x;  // = c on write phase
  for (int i = t; i < 256 * 71; i += 256) {
    int c = i / 71;
    int w = i - c * 71;
    float f = X[(((size_t)(b * 256 + c)) * 71 + h) * 71 + w];
    xl[c * 73 + w] = f2bf(f);
  }
  __syncthreads();
  const size_t obase = (size_t)b * XT_BSTRIDE + (size_t)h * XT_HSTRIDE;
  for (int s = 0; s < 71; ++s) {
    int par = (s >= 36) ? 1 : 0;
    int j = s - par * 36;
    int w = 2 * j + par;
    xT[obase + par * 9216 + j * 256 + t] = xl[t * 73 + w];
  }
}

// ---- conv as implicit GEMM: U[n][m] = sum_k Wb[m][k] * X[n][k] ----
// block = 64m x 256n, BK=32, 4 waves each 64m x 64n of 32x32x16 MFMA
// m-tile pinned per XCD so the 2.65MB A working set stays L2-resident.
__global__ __launch_bounds__(256) void conv_gemm(const u16* __restrict__ Wb,
                                                 const u16* __restrict__ xT,
                                                 u16* __restrict__ U) {
  __shared__ __align__(16) u16 As[64 * 32];    // 4KB
  __shared__ __align__(16) u16 Bs[256 * 32];   // 16KB
  const int tid = threadIdx.x;
  const int bx = blockIdx.x;
  const int xcd = bx & 7;
  const int q = bx >> 3;            // 0..255 per XCD
  const int mt = xcd + 8 * (q >> 7);
  const int nt = q & 127;
  const int m0 = mt * 64;
  const int n0 = nt * 256;
  const int lane = tid & 63;
  const int wave = tid >> 6;

  // staging: thread -> (row = tid>>2, k8 = (tid&3)*8); LDS dest = wavebase + lane*16B
  const int sr = tid >> 2;
  const int sq = (tid & 3) * 8;
  const u16* aP = Wb + (size_t)(m0 + sr) * K_TOT + sq;
  const u16* bP[4];
#pragma unroll
  for (int ch = 0; ch < 4; ++ch) {
    const int ng = n0 + ch * 64 + sr;
    const size_t nb = (size_t)(ng >> 10) * XT_BSTRIDE +
                      (size_t)(((ng >> 5) & 31) * 2) * XT_HSTRIDE + (size_t)(ng & 31) * 256;
    bP[ch] = xT + nb + sq;
  }
  u16* AsW = As + wave * 512;       // wave-uniform LDS base (1024B per wave)
  u16* BsW = Bs + wave * 512;

  f32x16 acc[2][2];
#pragma unroll
  for (int i = 0; i < 2; ++i)
#pragma unroll
    for (int j = 0; j < 2; ++j)
#pragma unroll
      for (int r = 0; r < 16; ++r) acc[i][j][r] = 0.f;

  // 32x32x16 A/B fragment: row = lane&31, k = (lane>>5)*8 + j  (8 contiguous k)
  const int fr = (lane & 31) * 32 + (lane >> 5) * 8;

  for (int p = 0; p < 81; ++p) {
    const int kh = p / 9;
    const int kw = p - kh * 9;
    const int koffA = p * 256;
    const int koffB = kh * XT_HSTRIDE + (kw & 1) * 9216 + (kw >> 1) * 256;
    for (int c0 = 0; c0 < 256; c0 += 32) {
      __syncthreads();
      glds16(aP + koffA + c0, AsW);
      glds16(bP[0] + koffB + c0, BsW);
      glds16(bP[1] + koffB + c0, BsW + 2048);
      glds16(bP[2] + koffB + c0, BsW + 4096);
      glds16(bP[3] + koffB + c0, BsW + 6144);
      __syncthreads();
      short8 af[2][2], bfv[2][2];
#pragma unroll
      for (int i = 0; i < 2; ++i)
#pragma unroll
        for (int h = 0; h < 2; ++h) {
          af[i][h]  = *(const short8*)&As[i * 32 * 32 + h * 16 + fr];
          bfv[i][h] = *(const short8*)&Bs[(wave * 64 + i * 32) * 32 + h * 16 + fr];
        }
#pragma unroll
      for (int h = 0; h < 2; ++h)
#pragma unroll
        for (int i = 0; i < 2; ++i)
#pragma unroll
          for (int j = 0; j < 2; ++j)
            acc[i][j] = __builtin_amdgcn_mfma_f32_32x32x16_bf16(af[i][h], bfv[j][h], acc[i][j], 0, 0, 0);
    }
  }

  // C/D 32x32: col = lane&31 (n-local), row = (reg&3) + 8*(reg>>2) + 4*(lane>>5)
  const int cn = lane & 31;
  const int q4 = (lane >> 5) * 4;
#pragma unroll
  for (int i = 0; i < 2; ++i) {
#pragma unroll
    for (int j = 0; j < 2; ++j) {
      const int ng = n0 + wave * 64 + j * 32 + cn;
      u16* up = U + (size_t)ng * M_TOT + m0 + i * 32;
#pragma unroll
      for (int g = 0; g < 4; ++g) {
        const int row0 = g * 8 + q4;   // rows row0..row0+3 are m-consecutive
        uint2 pk;
        pk.x = (uint32_t)f2bf(acc[i][j][g * 4 + 0]) | ((uint32_t)f2bf(acc[i][j][g * 4 + 1]) << 16);
        pk.y = (uint32_t)f2bf(acc[i][j][g * 4 + 2]) | ((uint32_t)f2bf(acc[i][j][g * 4 + 3]) << 16);
        *(uint2*)(up + row0) = pk;
      }
    }
  }
}

// ---- dynamic routing: one block per (b,hp); thread = (nc,oc) ----
// U is [n][m]: per-wp loads are fully coalesced across the 1024 threads.
__global__ __launch_bounds__(1024) void routing_k(const u16* __restrict__ U,
                                                  const float* __restrict__ bias,
                                                  float* __restrict__ out) {
  const int t = threadIdx.x;       // m = nc*32 + oc
  const int bx = blockIdx.x;
  const int b = bx >> 5;
  const int hp = bx & 31;
  const int oc = t & 31;
  const int nc = t >> 5;
  __shared__ float sm[1024];

  float u_r[32];
  {
    const u16* ub = U + (size_t)(b * 1024 + hp * 32) * M_TOT + t;
    const float bs = bias[t];
#pragma unroll
    for (int w = 0; w < 32; ++w) u_r[w] = bf2f(ub[(size_t)w * M_TOT]) + bs;
  }

  float bij = 0.f;
  float s[32];
  float scale = 0.f;

  for (int it = 0; it < 3; ++it) {
    sm[t] = bij;
    __syncthreads();
    // softmax over nc for this oc (values are small; no max-subtract needed)
    float den = 0.f;
#pragma unroll
    for (int i = 0; i < 32; ++i) den += __expf(sm[i * 32 + oc]);
    const float c = __expf(bij) / den;
    // s[nc][wp] = sum_oc c*u_hat : butterfly allreduce across the 32-lane oc group
#pragma unroll
    for (int w = 0; w < 32; ++w) s[w] = c * u_r[w];
#pragma unroll
    for (int off = 1; off < 32; off <<= 1) {
#pragma unroll
      for (int w = 0; w < 32; ++w) s[w] += __shfl_xor(s[w], off, 64);
    }
    // squash over wp
    float n2 = 0.f;
#pragma unroll
    for (int w = 0; w < 32; ++w) n2 += s[w] * s[w];
    scale = sqrtf(n2) / (1.f + n2);
    if (it < 2) {
      // b_ij += sum_wp u_hat * v ;  v = scale*s
      float agr = 0.f;
#pragma unroll
      for (int w = 0; w < 32; ++w) agr += u_r[w] * s[w];
      bij += scale * agr;
    }
    __syncthreads();
  }

  // lane oc writes element wp==oc (register-select to avoid scratch)
  float val = s[0];
#pragma unroll
  for (int i = 1; i < 32; ++i) val = (oc == i) ? s[i] : val;
  out[(size_t)((b * 32 + nc) * 32 + hp) * 32 + oc] = scale * val;
}

extern "C" void kernel_launch(void* const* d_in, const int* in_sizes, int n_in,
                              void* d_out, int out_size, void* d_ws, size_t ws_size,
                              hipStream_t stream) {
  const float* x = (const float*)d_in[0];
  const float* W = (const float*)d_in[1];
  const float* bias = (const float*)d_in[2];

  // workspace layout (bytes): Wb 42,467,328 | xT 83,755,008 | U 67,108,864  (total 193.3 MB)
  u16* Wb = (u16*)d_ws;
  u16* xT = (u16*)((char*)d_ws + 42467328u);
  u16* U  = (u16*)((char*)d_ws + 126222336u);
  float* out = (float*)d_out;

  pack_w<<<dim3(1024), dim3(256), 0, stream>>>(W, Wb);
  pack_x<<<dim3(71, 32), dim3(256), 0, stream>>>(x, xT);
  conv_gemm<<<dim3(2048), dim3(256), 0, stream>>>(Wb, xT, U);
  routing_k<<<dim3(1024), dim3(1024), 0, stream>>>(U, bias, out);
}